// Round 11
// baseline (231.942 us; speedup 1.0000x reference)
//
#include <hip/hip_runtime.h>
#include <hip/hip_fp16.h>

// GCN: 3x (GEMM(+BN fold from gstats) -> CSR aggregate(+atomic BN partials)),
// then mean-pool + head.
// Sizes fixed: N=65536 nodes, E=1048576 edges, F=H=64, 64 graphs, 16 classes.
//
// r8 baseline (188us): 4096-edge bin, scalar-LDS gemm, LDS-staged agg windows.
// r9 ticket+fence = L2 storm (REVERTED). r10 bundled 8192-bin + float4-gemm +
// atomic-stats-fold = 231us. r11: revert bin+gemm to r8 exactly; keep ONLY the
// atomic stats fold (line-padded float atomicAdd, no fences) to isolate it.

#define NBKT 512      // bucket = dst >> 7 (128 nodes per bucket)
#define CAP  4096     // slots per bucket (avg fill 2048)
#define BSTRIDE 16    // padded: one counter per 64B line

__device__ inline unsigned pack2h(float a, float b) {
    __half ha = __float2half_rn(a), hb = __float2half_rn(b);
    unsigned short ua = *(unsigned short*)&ha, ub = *(unsigned short*)&hb;
    return (unsigned)ua | ((unsigned)ub << 16);
}

__device__ inline void acc8(float* a, uint4 u) {
    __half2* hp = (__half2*)&u;
#pragma unroll
    for (int i = 0; i < 4; ++i) {
        float2 f = __half22float2(hp[i]);
        a[2 * i] += f.x;
        a[2 * i + 1] += f.y;
    }
}

__global__ void k_binit(int* __restrict__ bcur) {
    int t = blockIdx.x * 256 + threadIdx.x;
    if (t < NBKT) bcur[t * BSTRIDE] = t * CAP;
}

// partition edges into NBKT dst-buckets; entries packed (src<<7)|(dst&127)
// 4096 edges/block (r8-proven: 256 blocks, 28KB LDS)
__global__ void k_bin(const int* __restrict__ ei, int E, int* __restrict__ bcur,
                      int* __restrict__ buck) {
    __shared__ int sd[4096];
    __shared__ unsigned short bk[4096];
    __shared__ int cnt[NBKT], off[NBKT];
    int t = threadIdx.x;
    int base = blockIdx.x * 4096;
    for (int i = t; i < NBKT; i += 256) cnt[i] = 0;
    __syncthreads();
#pragma unroll
    for (int k = 0; k < 16; ++k) {
        int i = k * 256 + t;
        int e = base + i;
        int s = ei[e], d = ei[E + e];
        sd[i] = (s << 7) | (d & 127);
        int b = d >> 7;
        bk[i] = (unsigned short)b;
        atomicAdd(&cnt[b], 1);
    }
    __syncthreads();
    for (int b = t; b < NBKT; b += 256) {
        int c = cnt[b];
        off[b] = c ? atomicAdd(&bcur[b * BSTRIDE], c) : 0;
    }
    __syncthreads();
#pragma unroll
    for (int k = 0; k < 16; ++k) {
        int i = k * 256 + t;
        int b = bk[i];
        int p = atomicAdd(&off[b], 1);
        buck[p] = sd[i];
    }
}

// exclusive scan over bucket counts; zeros gstats (3 layers) / psum / pcnt
__global__ void k_scanB(const int* __restrict__ bcur, int* __restrict__ bbase,
                        int* __restrict__ rowptr, float* __restrict__ gstats,
                        float* __restrict__ psum, float* __restrict__ pcnt,
                        int N, int E) {
    __shared__ int s[NBKT];
    int t = threadIdx.x;
    int v = bcur[t * BSTRIDE] - t * CAP;
    s[t] = v;
    __syncthreads();
    for (int o = 1; o < NBKT; o <<= 1) {
        int x = (t >= o) ? s[t - o] : 0;
        __syncthreads();
        s[t] += x;
        __syncthreads();
    }
    bbase[t] = s[t] - v;
    for (int i = t; i < 3 * 2048; i += NBKT) gstats[i] = 0.0f;
    for (int i = t; i < 4096; i += NBKT) psum[i] = 0.0f;
    if (t < 64) pcnt[t] = 0.0f;
    if (t == 0) rowptr[N] = E;
}

// per bucket: count node degrees in LDS, local 128-scan -> rowptr/dinv, scatter csr
__global__ void k_place(const int* __restrict__ bcur, const int* __restrict__ buck,
                        const int* __restrict__ bbase, int* __restrict__ rowptr,
                        float* __restrict__ dinv, int* __restrict__ csr) {
    __shared__ int dc[128], sc[128], cur[128];
    int b = blockIdx.x, t = threadIdx.x;
    if (t < 128) dc[t] = 0;
    __syncthreads();
    int beg = b * CAP, end = bcur[b * BSTRIDE];
    for (int i = beg + t; i < end; i += 256) atomicAdd(&dc[buck[i] & 127], 1);
    __syncthreads();
    int v = (t < 128) ? dc[t] : 0;
    if (t < 128) sc[t] = v;
    __syncthreads();
    for (int o = 1; o < 128; o <<= 1) {
        int x = 0;
        if (t < 128 && t >= o) x = sc[t - o];
        __syncthreads();
        if (t < 128) sc[t] += x;
        __syncthreads();
    }
    if (t < 128) {
        int r = bbase[b] + sc[t] - v;   // exclusive
        rowptr[b * 128 + t] = r;
        cur[t] = r;
        dinv[b * 128 + t] = rsqrtf((float)(v + 1));  // +1 self loop
    }
    __syncthreads();
    for (int i = beg + t; i < end; i += 256) {
        int e = buck[i];
        int p = atomicAdd(&cur[e & 127], 1);
        csr[p] = e >> 7;
    }
}

// y[n][j] = fp16( dinv[n] * ( sum_f hnorm[n][f]*W[f][j] + brow[j] ) )
// HS: derive mean/rstd of the PREVIOUS layer from gstats; fold into Ws/brow.
// r8-proven body: block 256 threads, 64 rows/block; thread = 4x4 tile;
// hs stride 65, scalar inner-loop reads.
template <int HIN, int HS>
__global__ void k_gemm(const void* __restrict__ hv, const float* __restrict__ W,
                       const float* __restrict__ gstats, float invN,
                       const float* __restrict__ dinv, __half* __restrict__ y) {
    __shared__ float Ws[4096];        // [f][c] 64x64, scaled by rstd[f]
    __shared__ float hs[64 * 65];     // [row][f], stride 65
    __shared__ float sm[64], sr[64], bs[64];
    int t = threadIdx.x;
    int rowBase = blockIdx.x * 64;
    if (t < 64) {
        if (HS) {
            float S = gstats[t * 16];
            float Q = gstats[(64 + t) * 16];
            float m = S * invN;
            float var = Q * invN - m * m;
            sm[t] = m;
            sr[t] = rsqrtf(var + 1e-5f);
        } else {
            sm[t] = 0.0f;
            sr[t] = 1.0f;
        }
    }
    __syncthreads();
#pragma unroll
    for (int k = 0; k < 4; ++k) {
        int i = t + k * 256;              // float4 index; row f = i>>4
        float4 wv = ((const float4*)W)[i];
        float s = sr[i >> 4];
        wv.x *= s; wv.y *= s; wv.z *= s; wv.w *= s;
        ((float4*)Ws)[i] = wv;
    }
    if (HIN) {
        const uint4* src = (const uint4*)((const __half*)hv + (size_t)rowBase * 64);
#pragma unroll
        for (int k = 0; k < 2; ++k) {
            int i = t + k * 256;          // 0..511 uint4s; each = 8 halves
            int row = i >> 3, c8 = i & 7;
            uint4 u = src[i];
            const __half2* hp = (const __half2*)&u;
            float* dst = &hs[row * 65 + c8 * 8];
#pragma unroll
            for (int j = 0; j < 4; ++j) {
                dst[2 * j + 0] = __low2float(hp[j]);
                dst[2 * j + 1] = __high2float(hp[j]);
            }
        }
    } else {
        const float4* src = (const float4*)((const float*)hv + (size_t)rowBase * 64);
#pragma unroll
        for (int k = 0; k < 4; ++k) {
            int i = t + k * 256;
            int row = i >> 4, c4 = i & 15;
            float4 v = src[i];
            float* dst = &hs[row * 65 + c4 * 4];
            dst[0] = v.x; dst[1] = v.y; dst[2] = v.z; dst[3] = v.w;
        }
    }
    __syncthreads();
    if (t < 64) {
        float acc = 0.0f;
        for (int f = 0; f < 64; ++f) acc += sm[f] * Ws[f * 64 + t];
        bs[t] = -acc;
    }
    __syncthreads();
    int rg = t >> 4;   // 0..15
    int cg = t & 15;   // 0..15
    float4 a0, a1, a2, a3;
    {
        float bx = bs[cg * 4 + 0], by = bs[cg * 4 + 1];
        float bz = bs[cg * 4 + 2], bw = bs[cg * 4 + 3];
        a0 = {bx, by, bz, bw}; a1 = a0; a2 = a0; a3 = a0;
    }
    const float* h0 = &hs[(rg * 4 + 0) * 65];
    const float* h1 = &hs[(rg * 4 + 1) * 65];
    const float* h2 = &hs[(rg * 4 + 2) * 65];
    const float* h3 = &hs[(rg * 4 + 3) * 65];
#pragma unroll 4
    for (int f = 0; f < 64; ++f) {
        float4 wv = ((float4*)Ws)[f * 16 + cg];
        float v0 = h0[f], v1 = h1[f], v2 = h2[f], v3 = h3[f];
        a0.x += v0 * wv.x; a0.y += v0 * wv.y; a0.z += v0 * wv.z; a0.w += v0 * wv.w;
        a1.x += v1 * wv.x; a1.y += v1 * wv.y; a1.z += v1 * wv.z; a1.w += v1 * wv.w;
        a2.x += v2 * wv.x; a2.y += v2 * wv.y; a2.z += v2 * wv.z; a2.w += v2 * wv.w;
        a3.x += v3 * wv.x; a3.y += v3 * wv.y; a3.z += v3 * wv.z; a3.w += v3 * wv.w;
    }
    float d0 = dinv[rowBase + rg * 4 + 0];
    float d1 = dinv[rowBase + rg * 4 + 1];
    float d2 = dinv[rowBase + rg * 4 + 2];
    float d3 = dinv[rowBase + rg * 4 + 3];
    uint2* y2 = (uint2*)y;
    size_t ob = (size_t)(rowBase + rg * 4) * 16 + cg;
    y2[ob + 0]  = {pack2h(a0.x * d0, a0.y * d0), pack2h(a0.z * d0, a0.w * d0)};
    y2[ob + 16] = {pack2h(a1.x * d1, a1.y * d1), pack2h(a1.z * d1, a1.w * d1)};
    y2[ob + 32] = {pack2h(a2.x * d2, a2.y * d2), pack2h(a2.z * d2, a2.w * d2)};
    y2[ob + 48] = {pack2h(a3.x * d3, a3.y * d3), pack2h(a3.z * d3, a3.w * d3)};
}

// out[n] = relu?( dinv[n]*(y[n] + sum_{src} y[src]) + bias ), stored fp16.
// Block = 64 consecutive nodes; csr window staged in LDS; octet (8 lanes) = 1 node;
// lane j = feats 8j..8j+7 (uint4 row); 4-deep unroll -> 32 loads in flight/wave.
// BN partials: block-reduce in LDS, then 128 line-padded float atomicAdds (no fence).
template <int RELU>
__global__ __launch_bounds__(512) void k_agg(
        const __half* __restrict__ y, const int* __restrict__ rowptr,
        const int* __restrict__ csr, const float* __restrict__ dinv,
        const float* __restrict__ bias, __half* __restrict__ hout,
        float* __restrict__ gstats, int N) {
    __shared__ int lcsr[2048];
    __shared__ int lrp[65];
    __shared__ float SW[16][64];            // [0..7]=sum per wave, [8..15]=sumsq
    int t = threadIdx.x;
    int lane = t & 63, wid = t >> 6;        // 8 waves
    int o = lane >> 3, j = lane & 7;        // octet 0..7, lane-in-octet 0..7
    int nodeBase = blockIdx.x * 64;
    if (t < 65) lrp[t] = rowptr[nodeBase + t];
    __syncthreads();
    int wbase = lrp[0];
    int wlen = lrp[64] - wbase;
    bool fits = (wlen <= 2048);
    if (fits)
        for (int i = t; i < wlen; i += 512) lcsr[i] = csr[wbase + i];
    __syncthreads();

    int n = nodeBase + wid * 8 + o;
    int beg = lrp[wid * 8 + o] - wbase;
    int d = lrp[wid * 8 + o + 1] - wbase - beg;
    const uint4* y4 = (const uint4*)y;      // row = 8 uint4 = 128B
    float a[8] = {0, 0, 0, 0, 0, 0, 0, 0};

    if (fits) {
        const int* cp = lcsr + beg;
        int k = 0;
        for (; k + 4 <= d; k += 4) {
            int s0 = cp[k], s1 = cp[k + 1], s2 = cp[k + 2], s3 = cp[k + 3];
            uint4 u0 = y4[(size_t)s0 * 8 + j];
            uint4 u1 = y4[(size_t)s1 * 8 + j];
            uint4 u2 = y4[(size_t)s2 * 8 + j];
            uint4 u3 = y4[(size_t)s3 * 8 + j];
            acc8(a, u0); acc8(a, u1); acc8(a, u2); acc8(a, u3);
        }
        for (; k < d; ++k) {
            uint4 u0 = y4[(size_t)cp[k] * 8 + j];
            acc8(a, u0);
        }
    } else {                                 // ~never (window 32 sigma below cap)
        const int* cp = csr + wbase + beg;
        int k = 0;
        for (; k + 4 <= d; k += 4) {
            int s0 = cp[k], s1 = cp[k + 1], s2 = cp[k + 2], s3 = cp[k + 3];
            uint4 u0 = y4[(size_t)s0 * 8 + j];
            uint4 u1 = y4[(size_t)s1 * 8 + j];
            uint4 u2 = y4[(size_t)s2 * 8 + j];
            uint4 u3 = y4[(size_t)s3 * 8 + j];
            acc8(a, u0); acc8(a, u1); acc8(a, u2); acc8(a, u3);
        }
        for (; k < d; ++k) {
            uint4 u0 = y4[(size_t)cp[k] * 8 + j];
            acc8(a, u0);
        }
    }
    uint4 us = y4[(size_t)n * 8 + j];       // self term
    acc8(a, us);

    float dv = dinv[n];
    const float4* b4 = (const float4*)bias;
    float4 blo = b4[j * 2], bhi = b4[j * 2 + 1];
    float v[8];
    v[0] = a[0] * dv + blo.x; v[1] = a[1] * dv + blo.y;
    v[2] = a[2] * dv + blo.z; v[3] = a[3] * dv + blo.w;
    v[4] = a[4] * dv + bhi.x; v[5] = a[5] * dv + bhi.y;
    v[6] = a[6] * dv + bhi.z; v[7] = a[7] * dv + bhi.w;
    if (RELU) {
#pragma unroll
        for (int i = 0; i < 8; ++i) v[i] = fmaxf(v[i], 0.0f);
    }
    uint4 ov;
    ov.x = pack2h(v[0], v[1]); ov.y = pack2h(v[2], v[3]);
    ov.z = pack2h(v[4], v[5]); ov.w = pack2h(v[6], v[7]);
    ((uint4*)hout)[(size_t)n * 8 + j] = ov;

    // BN partials: combine octets (nodes) then one atomic per feature per block
    float q[8];
#pragma unroll
    for (int i = 0; i < 8; ++i) q[i] = v[i] * v[i];
#pragma unroll
    for (int st = 8; st <= 32; st <<= 1) {
#pragma unroll
        for (int i = 0; i < 8; ++i) {
            v[i] += __shfl_xor(v[i], st);
            q[i] += __shfl_xor(q[i], st);
        }
    }
    if (o == 0) {
#pragma unroll
        for (int i = 0; i < 8; ++i) {
            SW[wid][j * 8 + i] = v[i];
            SW[8 + wid][j * 8 + i] = q[i];
        }
    }
    __syncthreads();
    if (t < 64) {
        float s = 0.0f, qq = 0.0f;
#pragma unroll
        for (int w = 0; w < 8; ++w) {
            s += SW[w][t];
            qq += SW[8 + w][t];
        }
        atomicAdd(&gstats[t * 16], s);            // line-padded: 128 distinct lines
        atomicAdd(&gstats[(64 + t) * 16], qq);
    }
}

// mean pool; BN of final layer derived from gstats on the fly; batch sorted ->
// per-run register accum, few float atomics into psum/pcnt.
__global__ void k_pool(const __half* __restrict__ h, const int* __restrict__ batch,
                       const float* __restrict__ gstats, float invN,
                       float* __restrict__ psum, float* __restrict__ pcnt) {
    int lane = threadIdx.x;
    int base = blockIdx.x * 64;
    float S = gstats[lane * 16], Q = gstats[(64 + lane) * 16];
    float m = S * invN;
    float r = rsqrtf(Q * invN - m * m + 1e-5f);
    int cur = batch[base];
    float acc = 0.0f;
    int runlen = 0;
    for (int i = 0; i < 64; ++i) {
        int n = base + i;
        int g = batch[n];
        if (g != cur) {
            atomicAdd(&psum[cur * 64 + lane], acc);
            if (lane == 0) atomicAdd(&pcnt[cur], (float)runlen);
            acc = 0.0f;
            runlen = 0;
            cur = g;
        }
        acc += (__half2float(h[(size_t)n * 64 + lane]) - m) * r;
        runlen++;
    }
    atomicAdd(&psum[cur * 64 + lane], acc);
    if (lane == 0) atomicAdd(&pcnt[cur], (float)runlen);
}

// logits = pooled @ clfW^T + clfb ; softmax over 16 classes. 1 block x 1024 threads.
__global__ void k_head(const float* __restrict__ psum, const float* __restrict__ pcnt,
                       const float* __restrict__ clfW, const float* __restrict__ clfb,
                       float* __restrict__ out) {
    __shared__ float ps[64 * 64];
    __shared__ float wl[16 * 64];
    __shared__ float ci[64];
    int t = threadIdx.x;
    ((float4*)ps)[t] = ((const float4*)psum)[t];
    if (t < 256) ((float4*)wl)[t] = ((const float4*)clfW)[t];
    if (t < 64) ci[t] = 1.0f / fmaxf(pcnt[t], 1.0f);
    __syncthreads();
    int g = t >> 4, c = t & 15;
    float acc = 0.0f;
#pragma unroll 8
    for (int f = 0; f < 64; ++f) acc += ps[g * 64 + f] * wl[c * 64 + f];
    acc = acc * ci[g] + clfb[c];
    float mx = acc;
    for (int o = 1; o < 16; o <<= 1) mx = fmaxf(mx, __shfl_xor(mx, o, 16));
    float e = __expf(acc - mx);
    float s = e;
    for (int o = 1; o < 16; o <<= 1) s += __shfl_xor(s, o, 16);
    out[t] = e / s;
}

extern "C" void kernel_launch(void* const* d_in, const int* in_sizes, int n_in,
                              void* d_out, int out_size, void* d_ws, size_t ws_size,
                              hipStream_t stream) {
    const float* x    = (const float*)d_in[0];
    const int*   ei   = (const int*)d_in[1];
    const int*   bat  = (const int*)d_in[2];
    const float* W0   = (const float*)d_in[3];
    const float* b0   = (const float*)d_in[4];
    const float* W1   = (const float*)d_in[5];
    const float* b1   = (const float*)d_in[6];
    const float* W2   = (const float*)d_in[7];
    const float* b2   = (const float*)d_in[8];
    const float* clfW = (const float*)d_in[9];
    const float* clfb = (const float*)d_in[10];
    float* out = (float*)d_out;

    const int N = in_sizes[0] / 64;   // 65536
    const int E = in_sizes[1] / 2;    // 1048576
    const int AB = N / 64;            // 1024 agg blocks

    char* w = (char*)d_ws;
    size_t off = 0;
    auto take = [&](size_t bytes) -> void* {
        off = (off + 255) & ~(size_t)255;
        void* p = w + off;
        off += bytes;
        return p;
    };
    int*    rowptr   = (int*)take((size_t)(N + 1) * 4);
    int*    bcur     = (int*)take((size_t)NBKT * BSTRIDE * 4);
    int*    bbase    = (int*)take((size_t)NBKT * 4);
    float*  dinv     = (float*)take((size_t)N * 4);
    int*    csr      = (int*)take((size_t)E * 4);
    __half* y        = (__half*)take((size_t)N * 64 * 2);
    __half* hA       = (__half*)take((size_t)N * 64 * 2);
    __half* hB       = (__half*)take((size_t)N * 64 * 2);
    float*  gstats   = (float*)take((size_t)3 * 2048 * 4);  // 3 layers, line-padded
    float*  psum     = (float*)take(64 * 64 * 4);
    float*  pcnt     = (float*)take(64 * 4);
    // buck (NBKT*CAP ints = 8MB) overlaid on hB (8MB fp16): buck dead after k_place,
    // hB first written in layer-1 k_agg.
    int* buck = (int*)hB;
    float* gs0 = gstats;
    float* gs1 = gstats + 2048;
    float* gs2 = gstats + 4096;

    const float invN = 1.0f / (float)N;

    k_binit<<<(NBKT + 255) / 256, 256, 0, stream>>>(bcur);
    k_bin<<<E / 4096, 256, 0, stream>>>(ei, E, bcur, buck);
    k_scanB<<<1, NBKT, 0, stream>>>(bcur, bbase, rowptr, gstats, psum, pcnt, N, E);
    k_place<<<NBKT, 256, 0, stream>>>(bcur, buck, bbase, rowptr, dinv, csr);

    // layer 0 (input x fp32, no BN on input)
    k_gemm<0, 0><<<N / 64, 256, 0, stream>>>(x, W0, nullptr, invN, dinv, y);
    k_agg<1><<<AB, 512, 0, stream>>>(y, rowptr, csr, dinv, b0, hA, gs0, N);
    // layer 1 (BN of layer0 derived from gs0 inside gemm)
    k_gemm<1, 1><<<N / 64, 256, 0, stream>>>(hA, W1, gs0, invN, dinv, y);
    k_agg<1><<<AB, 512, 0, stream>>>(y, rowptr, csr, dinv, b1, hB, gs1, N);
    // layer 2 (no relu)
    k_gemm<1, 1><<<N / 64, 256, 0, stream>>>(hB, W2, gs1, invN, dinv, y);
    k_agg<0><<<AB, 512, 0, stream>>>(y, rowptr, csr, dinv, b2, hA, gs2, N);

    // pool (BN of layer2 from gs2) + head
    k_pool<<<N / 64, 64, 0, stream>>>(hA, bat, gs2, invN, psum, pcnt);
    k_head<<<1, 1024, 0, stream>>>(psum, pcnt, clfW, clfb, out);
}

// Round 12
// 192.288 us; speedup vs baseline: 1.2062x; 1.2062x over previous
//
#include <hip/hip_runtime.h>
#include <hip/hip_fp16.h>

// GCN: 3x (GEMM(+BN fold from gstats) -> CSR aggregate(+slot-replicated atomic
// BN partials)), then mean-pool + head.
// Sizes fixed: N=65536 nodes, E=1048576 edges, F=H=64, 64 graphs, 16 classes.
//
// r8 baseline (188us): 4096-edge bin, scalar-LDS gemm, LDS-staged agg windows.
// r9 ticket+fence = L2 storm. r10/r11: single-copy atomic stats fold = 13us
// same-line atomic tail per agg (1024 serialized adds/line @ ~13ns = r3 lesson).
// r12: 16-slot replicated gstats (slot = blockIdx&15, line-padded) -> 64
// serialized adds/line (~0.8us tail); consumers sum the 16 slots.

#define NBKT 512      // bucket = dst >> 7 (128 nodes per bucket)
#define CAP  4096     // slots per bucket (avg fill 2048)
#define BSTRIDE 16    // padded: one counter per 64B line
#define NSLOT 16      // gstats replication factor
#define GSL   2048    // floats per gstats slot (128 features x 16-stride)

__device__ inline unsigned pack2h(float a, float b) {
    __half ha = __float2half_rn(a), hb = __float2half_rn(b);
    unsigned short ua = *(unsigned short*)&ha, ub = *(unsigned short*)&hb;
    return (unsigned)ua | ((unsigned)ub << 16);
}

__device__ inline void acc8(float* a, uint4 u) {
    __half2* hp = (__half2*)&u;
#pragma unroll
    for (int i = 0; i < 4; ++i) {
        float2 f = __half22float2(hp[i]);
        a[2 * i] += f.x;
        a[2 * i + 1] += f.y;
    }
}

// init bcur + zero gstats (3 layers x 16 slots) / psum / pcnt. 128 blocks.
__global__ void k_binit(int* __restrict__ bcur, float* __restrict__ gstats,
                        float* __restrict__ psum, float* __restrict__ pcnt) {
    int idx = blockIdx.x * 256 + threadIdx.x;   // 0..32767
    if (idx < NBKT) bcur[idx * BSTRIDE] = idx * CAP;
    for (int i = idx; i < 3 * NSLOT * GSL; i += 32768) gstats[i] = 0.0f;
    if (idx < 4096) psum[idx] = 0.0f;
    if (idx < 64) pcnt[idx] = 0.0f;
}

// partition edges into NBKT dst-buckets; entries packed (src<<7)|(dst&127)
// 4096 edges/block (r8-proven: 256 blocks, 28KB LDS)
__global__ void k_bin(const int* __restrict__ ei, int E, int* __restrict__ bcur,
                      int* __restrict__ buck) {
    __shared__ int sd[4096];
    __shared__ unsigned short bk[4096];
    __shared__ int cnt[NBKT], off[NBKT];
    int t = threadIdx.x;
    int base = blockIdx.x * 4096;
    for (int i = t; i < NBKT; i += 256) cnt[i] = 0;
    __syncthreads();
#pragma unroll
    for (int k = 0; k < 16; ++k) {
        int i = k * 256 + t;
        int e = base + i;
        int s = ei[e], d = ei[E + e];
        sd[i] = (s << 7) | (d & 127);
        int b = d >> 7;
        bk[i] = (unsigned short)b;
        atomicAdd(&cnt[b], 1);
    }
    __syncthreads();
    for (int b = t; b < NBKT; b += 256) {
        int c = cnt[b];
        off[b] = c ? atomicAdd(&bcur[b * BSTRIDE], c) : 0;
    }
    __syncthreads();
#pragma unroll
    for (int k = 0; k < 16; ++k) {
        int i = k * 256 + t;
        int b = bk[i];
        int p = atomicAdd(&off[b], 1);
        buck[p] = sd[i];
    }
}

// exclusive scan over bucket counts; sets rowptr[N]
__global__ void k_scanB(const int* __restrict__ bcur, int* __restrict__ bbase,
                        int* __restrict__ rowptr, int N, int E) {
    __shared__ int s[NBKT];
    int t = threadIdx.x;
    int v = bcur[t * BSTRIDE] - t * CAP;
    s[t] = v;
    __syncthreads();
    for (int o = 1; o < NBKT; o <<= 1) {
        int x = (t >= o) ? s[t - o] : 0;
        __syncthreads();
        s[t] += x;
        __syncthreads();
    }
    bbase[t] = s[t] - v;
    if (t == 0) rowptr[N] = E;
}

// per bucket: count node degrees in LDS, local 128-scan -> rowptr/dinv, scatter csr
__global__ void k_place(const int* __restrict__ bcur, const int* __restrict__ buck,
                        const int* __restrict__ bbase, int* __restrict__ rowptr,
                        float* __restrict__ dinv, int* __restrict__ csr) {
    __shared__ int dc[128], sc[128], cur[128];
    int b = blockIdx.x, t = threadIdx.x;
    if (t < 128) dc[t] = 0;
    __syncthreads();
    int beg = b * CAP, end = bcur[b * BSTRIDE];
    for (int i = beg + t; i < end; i += 256) atomicAdd(&dc[buck[i] & 127], 1);
    __syncthreads();
    int v = (t < 128) ? dc[t] : 0;
    if (t < 128) sc[t] = v;
    __syncthreads();
    for (int o = 1; o < 128; o <<= 1) {
        int x = 0;
        if (t < 128 && t >= o) x = sc[t - o];
        __syncthreads();
        if (t < 128) sc[t] += x;
        __syncthreads();
    }
    if (t < 128) {
        int r = bbase[b] + sc[t] - v;   // exclusive
        rowptr[b * 128 + t] = r;
        cur[t] = r;
        dinv[b * 128 + t] = rsqrtf((float)(v + 1));  // +1 self loop
    }
    __syncthreads();
    for (int i = beg + t; i < end; i += 256) {
        int e = buck[i];
        int p = atomicAdd(&cur[e & 127], 1);
        csr[p] = e >> 7;
    }
}

// y[n][j] = fp16( dinv[n] * ( sum_f hnorm[n][f]*W[f][j] + brow[j] ) )
// HS: derive mean/rstd of the PREVIOUS layer from 16-slot gstats; fold into Ws.
// r8-proven body: block 256 threads, 64 rows/block; thread = 4x4 tile.
template <int HIN, int HS>
__global__ void k_gemm(const void* __restrict__ hv, const float* __restrict__ W,
                       const float* __restrict__ gstats, float invN,
                       const float* __restrict__ dinv, __half* __restrict__ y) {
    __shared__ float Ws[4096];        // [f][c] 64x64, scaled by rstd[f]
    __shared__ float hs[64 * 65];     // [row][f], stride 65
    __shared__ float sm[64], sr[64], bs[64];
    int t = threadIdx.x;
    int rowBase = blockIdx.x * 64;
    if (t < 64) {
        if (HS) {
            float S = 0.0f, Q = 0.0f;
#pragma unroll
            for (int c = 0; c < NSLOT; ++c) {
                S += gstats[c * GSL + t * 16];
                Q += gstats[c * GSL + (64 + t) * 16];
            }
            float m = S * invN;
            float var = Q * invN - m * m;
            sm[t] = m;
            sr[t] = rsqrtf(var + 1e-5f);
        } else {
            sm[t] = 0.0f;
            sr[t] = 1.0f;
        }
    }
    __syncthreads();
#pragma unroll
    for (int k = 0; k < 4; ++k) {
        int i = t + k * 256;              // float4 index; row f = i>>4
        float4 wv = ((const float4*)W)[i];
        float s = sr[i >> 4];
        wv.x *= s; wv.y *= s; wv.z *= s; wv.w *= s;
        ((float4*)Ws)[i] = wv;
    }
    if (HIN) {
        const uint4* src = (const uint4*)((const __half*)hv + (size_t)rowBase * 64);
#pragma unroll
        for (int k = 0; k < 2; ++k) {
            int i = t + k * 256;          // 0..511 uint4s; each = 8 halves
            int row = i >> 3, c8 = i & 7;
            uint4 u = src[i];
            const __half2* hp = (const __half2*)&u;
            float* dst = &hs[row * 65 + c8 * 8];
#pragma unroll
            for (int j = 0; j < 4; ++j) {
                dst[2 * j + 0] = __low2float(hp[j]);
                dst[2 * j + 1] = __high2float(hp[j]);
            }
        }
    } else {
        const float4* src = (const float4*)((const float*)hv + (size_t)rowBase * 64);
#pragma unroll
        for (int k = 0; k < 4; ++k) {
            int i = t + k * 256;
            int row = i >> 4, c4 = i & 15;
            float4 v = src[i];
            float* dst = &hs[row * 65 + c4 * 4];
            dst[0] = v.x; dst[1] = v.y; dst[2] = v.z; dst[3] = v.w;
        }
    }
    __syncthreads();
    if (t < 64) {
        float acc = 0.0f;
        for (int f = 0; f < 64; ++f) acc += sm[f] * Ws[f * 64 + t];
        bs[t] = -acc;
    }
    __syncthreads();
    int rg = t >> 4;   // 0..15
    int cg = t & 15;   // 0..15
    float4 a0, a1, a2, a3;
    {
        float bx = bs[cg * 4 + 0], by = bs[cg * 4 + 1];
        float bz = bs[cg * 4 + 2], bw = bs[cg * 4 + 3];
        a0 = {bx, by, bz, bw}; a1 = a0; a2 = a0; a3 = a0;
    }
    const float* h0 = &hs[(rg * 4 + 0) * 65];
    const float* h1 = &hs[(rg * 4 + 1) * 65];
    const float* h2 = &hs[(rg * 4 + 2) * 65];
    const float* h3 = &hs[(rg * 4 + 3) * 65];
#pragma unroll 4
    for (int f = 0; f < 64; ++f) {
        float4 wv = ((float4*)Ws)[f * 16 + cg];
        float v0 = h0[f], v1 = h1[f], v2 = h2[f], v3 = h3[f];
        a0.x += v0 * wv.x; a0.y += v0 * wv.y; a0.z += v0 * wv.z; a0.w += v0 * wv.w;
        a1.x += v1 * wv.x; a1.y += v1 * wv.y; a1.z += v1 * wv.z; a1.w += v1 * wv.w;
        a2.x += v2 * wv.x; a2.y += v2 * wv.y; a2.z += v2 * wv.z; a2.w += v2 * wv.w;
        a3.x += v3 * wv.x; a3.y += v3 * wv.y; a3.z += v3 * wv.z; a3.w += v3 * wv.w;
    }
    float d0 = dinv[rowBase + rg * 4 + 0];
    float d1 = dinv[rowBase + rg * 4 + 1];
    float d2 = dinv[rowBase + rg * 4 + 2];
    float d3 = dinv[rowBase + rg * 4 + 3];
    uint2* y2 = (uint2*)y;
    size_t ob = (size_t)(rowBase + rg * 4) * 16 + cg;
    y2[ob + 0]  = {pack2h(a0.x * d0, a0.y * d0), pack2h(a0.z * d0, a0.w * d0)};
    y2[ob + 16] = {pack2h(a1.x * d1, a1.y * d1), pack2h(a1.z * d1, a1.w * d1)};
    y2[ob + 32] = {pack2h(a2.x * d2, a2.y * d2), pack2h(a2.z * d2, a2.w * d2)};
    y2[ob + 48] = {pack2h(a3.x * d3, a3.y * d3), pack2h(a3.z * d3, a3.w * d3)};
}

// out[n] = relu?( dinv[n]*(y[n] + sum_{src} y[src]) + bias ), stored fp16.
// Block = 64 consecutive nodes; csr window staged in LDS; octet (8 lanes) = 1 node;
// lane j = feats 8j..8j+7 (uint4 row); 4-deep unroll -> 32 loads in flight/wave.
// BN partials: block-reduce in LDS, then 128 atomicAdds into slot blockIdx&15.
template <int RELU>
__global__ __launch_bounds__(512) void k_agg(
        const __half* __restrict__ y, const int* __restrict__ rowptr,
        const int* __restrict__ csr, const float* __restrict__ dinv,
        const float* __restrict__ bias, __half* __restrict__ hout,
        float* __restrict__ gstats, int N) {
    __shared__ int lcsr[2048];
    __shared__ int lrp[65];
    __shared__ float SW[16][64];            // [0..7]=sum per wave, [8..15]=sumsq
    int t = threadIdx.x;
    int lane = t & 63, wid = t >> 6;        // 8 waves
    int o = lane >> 3, j = lane & 7;        // octet 0..7, lane-in-octet 0..7
    int nodeBase = blockIdx.x * 64;
    if (t < 65) lrp[t] = rowptr[nodeBase + t];
    __syncthreads();
    int wbase = lrp[0];
    int wlen = lrp[64] - wbase;
    bool fits = (wlen <= 2048);
    if (fits)
        for (int i = t; i < wlen; i += 512) lcsr[i] = csr[wbase + i];
    __syncthreads();

    int n = nodeBase + wid * 8 + o;
    int beg = lrp[wid * 8 + o] - wbase;
    int d = lrp[wid * 8 + o + 1] - wbase - beg;
    const uint4* y4 = (const uint4*)y;      // row = 8 uint4 = 128B
    float a[8] = {0, 0, 0, 0, 0, 0, 0, 0};

    if (fits) {
        const int* cp = lcsr + beg;
        int k = 0;
        for (; k + 4 <= d; k += 4) {
            int s0 = cp[k], s1 = cp[k + 1], s2 = cp[k + 2], s3 = cp[k + 3];
            uint4 u0 = y4[(size_t)s0 * 8 + j];
            uint4 u1 = y4[(size_t)s1 * 8 + j];
            uint4 u2 = y4[(size_t)s2 * 8 + j];
            uint4 u3 = y4[(size_t)s3 * 8 + j];
            acc8(a, u0); acc8(a, u1); acc8(a, u2); acc8(a, u3);
        }
        for (; k < d; ++k) {
            uint4 u0 = y4[(size_t)cp[k] * 8 + j];
            acc8(a, u0);
        }
    } else {                                 // ~never (window 32 sigma below cap)
        const int* cp = csr + wbase + beg;
        int k = 0;
        for (; k + 4 <= d; k += 4) {
            int s0 = cp[k], s1 = cp[k + 1], s2 = cp[k + 2], s3 = cp[k + 3];
            uint4 u0 = y4[(size_t)s0 * 8 + j];
            uint4 u1 = y4[(size_t)s1 * 8 + j];
            uint4 u2 = y4[(size_t)s2 * 8 + j];
            uint4 u3 = y4[(size_t)s3 * 8 + j];
            acc8(a, u0); acc8(a, u1); acc8(a, u2); acc8(a, u3);
        }
        for (; k < d; ++k) {
            uint4 u0 = y4[(size_t)cp[k] * 8 + j];
            acc8(a, u0);
        }
    }
    uint4 us = y4[(size_t)n * 8 + j];       // self term
    acc8(a, us);

    float dv = dinv[n];
    const float4* b4 = (const float4*)bias;
    float4 blo = b4[j * 2], bhi = b4[j * 2 + 1];
    float v[8];
    v[0] = a[0] * dv + blo.x; v[1] = a[1] * dv + blo.y;
    v[2] = a[2] * dv + blo.z; v[3] = a[3] * dv + blo.w;
    v[4] = a[4] * dv + bhi.x; v[5] = a[5] * dv + bhi.y;
    v[6] = a[6] * dv + bhi.z; v[7] = a[7] * dv + bhi.w;
    if (RELU) {
#pragma unroll
        for (int i = 0; i < 8; ++i) v[i] = fmaxf(v[i], 0.0f);
    }
    uint4 ov;
    ov.x = pack2h(v[0], v[1]); ov.y = pack2h(v[2], v[3]);
    ov.z = pack2h(v[4], v[5]); ov.w = pack2h(v[6], v[7]);
    ((uint4*)hout)[(size_t)n * 8 + j] = ov;

    // BN partials: combine octets (nodes) then one atomic per feature per block
    float q[8];
#pragma unroll
    for (int i = 0; i < 8; ++i) q[i] = v[i] * v[i];
#pragma unroll
    for (int st = 8; st <= 32; st <<= 1) {
#pragma unroll
        for (int i = 0; i < 8; ++i) {
            v[i] += __shfl_xor(v[i], st);
            q[i] += __shfl_xor(q[i], st);
        }
    }
    if (o == 0) {
#pragma unroll
        for (int i = 0; i < 8; ++i) {
            SW[wid][j * 8 + i] = v[i];
            SW[8 + wid][j * 8 + i] = q[i];
        }
    }
    __syncthreads();
    if (t < 64) {
        float s = 0.0f, qq = 0.0f;
#pragma unroll
        for (int w = 0; w < 8; ++w) {
            s += SW[w][t];
            qq += SW[8 + w][t];
        }
        float* gs = gstats + (blockIdx.x & (NSLOT - 1)) * GSL;  // replicated slot
        atomicAdd(&gs[t * 16], s);
        atomicAdd(&gs[(64 + t) * 16], qq);
    }
}

// mean pool; BN of final layer derived from 16-slot gstats; batch sorted ->
// per-run register accum, few float atomics into psum/pcnt.
__global__ void k_pool(const __half* __restrict__ h, const int* __restrict__ batch,
                       const float* __restrict__ gstats, float invN,
                       float* __restrict__ psum, float* __restrict__ pcnt) {
    int lane = threadIdx.x;
    int base = blockIdx.x * 64;
    float S = 0.0f, Q = 0.0f;
#pragma unroll
    for (int c = 0; c < NSLOT; ++c) {
        S += gstats[c * GSL + lane * 16];
        Q += gstats[c * GSL + (64 + lane) * 16];
    }
    float m = S * invN;
    float r = rsqrtf(Q * invN - m * m + 1e-5f);
    int cur = batch[base];
    float acc = 0.0f;
    int runlen = 0;
    for (int i = 0; i < 64; ++i) {
        int n = base + i;
        int g = batch[n];
        if (g != cur) {
            atomicAdd(&psum[cur * 64 + lane], acc);
            if (lane == 0) atomicAdd(&pcnt[cur], (float)runlen);
            acc = 0.0f;
            runlen = 0;
            cur = g;
        }
        acc += (__half2float(h[(size_t)n * 64 + lane]) - m) * r;
        runlen++;
    }
    atomicAdd(&psum[cur * 64 + lane], acc);
    if (lane == 0) atomicAdd(&pcnt[cur], (float)runlen);
}

// logits = pooled @ clfW^T + clfb ; softmax over 16 classes. 1 block x 1024 threads.
__global__ void k_head(const float* __restrict__ psum, const float* __restrict__ pcnt,
                       const float* __restrict__ clfW, const float* __restrict__ clfb,
                       float* __restrict__ out) {
    __shared__ float ps[64 * 64];
    __shared__ float wl[16 * 64];
    __shared__ float ci[64];
    int t = threadIdx.x;
    ((float4*)ps)[t] = ((const float4*)psum)[t];
    if (t < 256) ((float4*)wl)[t] = ((const float4*)clfW)[t];
    if (t < 64) ci[t] = 1.0f / fmaxf(pcnt[t], 1.0f);
    __syncthreads();
    int g = t >> 4, c = t & 15;
    float acc = 0.0f;
#pragma unroll 8
    for (int f = 0; f < 64; ++f) acc += ps[g * 64 + f] * wl[c * 64 + f];
    acc = acc * ci[g] + clfb[c];
    float mx = acc;
    for (int o = 1; o < 16; o <<= 1) mx = fmaxf(mx, __shfl_xor(mx, o, 16));
    float e = __expf(acc - mx);
    float s = e;
    for (int o = 1; o < 16; o <<= 1) s += __shfl_xor(s, o, 16);
    out[t] = e / s;
}

extern "C" void kernel_launch(void* const* d_in, const int* in_sizes, int n_in,
                              void* d_out, int out_size, void* d_ws, size_t ws_size,
                              hipStream_t stream) {
    const float* x    = (const float*)d_in[0];
    const int*   ei   = (const int*)d_in[1];
    const int*   bat  = (const int*)d_in[2];
    const float* W0   = (const float*)d_in[3];
    const float* b0   = (const float*)d_in[4];
    const float* W1   = (const float*)d_in[5];
    const float* b1   = (const float*)d_in[6];
    const float* W2   = (const float*)d_in[7];
    const float* b2   = (const float*)d_in[8];
    const float* clfW = (const float*)d_in[9];
    const float* clfb = (const float*)d_in[10];
    float* out = (float*)d_out;

    const int N = in_sizes[0] / 64;   // 65536
    const int E = in_sizes[1] / 2;    // 1048576
    const int AB = N / 64;            // 1024 agg blocks

    char* w = (char*)d_ws;
    size_t off = 0;
    auto take = [&](size_t bytes) -> void* {
        off = (off + 255) & ~(size_t)255;
        void* p = w + off;
        off += bytes;
        return p;
    };
    int*    rowptr   = (int*)take((size_t)(N + 1) * 4);
    int*    bcur     = (int*)take((size_t)NBKT * BSTRIDE * 4);
    int*    bbase    = (int*)take((size_t)NBKT * 4);
    float*  dinv     = (float*)take((size_t)N * 4);
    int*    csr      = (int*)take((size_t)E * 4);
    __half* y        = (__half*)take((size_t)N * 64 * 2);
    __half* hA       = (__half*)take((size_t)N * 64 * 2);
    __half* hB       = (__half*)take((size_t)N * 64 * 2);
    float*  gstats   = (float*)take((size_t)3 * NSLOT * GSL * 4);
    float*  psum     = (float*)take(64 * 64 * 4);
    float*  pcnt     = (float*)take(64 * 4);
    // buck (NBKT*CAP ints = 8MB) overlaid on hB (8MB fp16): buck dead after k_place,
    // hB first written in layer-1 k_agg.
    int* buck = (int*)hB;
    float* gs0 = gstats;
    float* gs1 = gstats + NSLOT * GSL;
    float* gs2 = gstats + 2 * NSLOT * GSL;

    const float invN = 1.0f / (float)N;

    k_binit<<<128, 256, 0, stream>>>(bcur, gstats, psum, pcnt);
    k_bin<<<E / 4096, 256, 0, stream>>>(ei, E, bcur, buck);
    k_scanB<<<1, NBKT, 0, stream>>>(bcur, bbase, rowptr, N, E);
    k_place<<<NBKT, 256, 0, stream>>>(bcur, buck, bbase, rowptr, dinv, csr);

    // layer 0 (input x fp32, no BN on input)
    k_gemm<0, 0><<<N / 64, 256, 0, stream>>>(x, W0, nullptr, invN, dinv, y);
    k_agg<1><<<AB, 512, 0, stream>>>(y, rowptr, csr, dinv, b0, hA, gs0, N);
    // layer 1 (BN of layer0 derived from gs0 inside gemm)
    k_gemm<1, 1><<<N / 64, 256, 0, stream>>>(hA, W1, gs0, invN, dinv, y);
    k_agg<1><<<AB, 512, 0, stream>>>(y, rowptr, csr, dinv, b1, hB, gs1, N);
    // layer 2 (no relu)
    k_gemm<1, 1><<<N / 64, 256, 0, stream>>>(hB, W2, gs1, invN, dinv, y);
    k_agg<0><<<AB, 512, 0, stream>>>(y, rowptr, csr, dinv, b2, hA, gs2, N);

    // pool (BN of layer2 from gs2) + head
    k_pool<<<N / 64, 64, 0, stream>>>(hA, bat, gs2, invN, psum, pcnt);
    k_head<<<1, 1024, 0, stream>>>(psum, pcnt, clfW, clfb, out);
}